// Round 13
// baseline (74.852 us; speedup 1.0000x reference)
//
#include <hip/hip_runtime.h>

// SetConv RBF: B=4, NQ=4096, NC=4096, DC=2, DY=8, fp32.
// out[b,q,0:8] = sum_c w(q,c)*y[c] / (den+1e-8); out[b,q,8] = den = sum_c w(q,c)
// w = exp2( (a0q + hc) + a1q*cx + a2q*cy ), negk = -log2(e)/(2*ls^2).
//
// MEASURED LAWS (R1-R12):
//  - dur_us includes 40-47us harness d_ws poison fill + ~10us fixed overhead
//    + ~3us reduce; controllable accum inferred ~17-20us.
//  - MFMA ladder: R8 ~28 -> R9 ~19.5us accum. R10 (packed math), R11 (2x
//    blocks), R12 (4x tiles/wave, half DS) ALL NEUTRAL at dur 73-75.
//    All pipes <50% busy -> residual = per-block fixed overhead (stage,
//    barrier, ramp/tail), not loop throughput.
//  - f16 weights FAIL (range); bf16 OK (fp32 exponent), absmax 0.25 < 0.99.
// R13: hoist B-fragment build to a one-shot prep kernel (512KB in d_ws,
// fully rewritten each call); accum loses the 16KB yfrag stage+transform,
// reads bfrag coalesced from global (L2) in-loop. LDS 22->6 KB.

#define BB 4
#define NQ 4096
#define NC 4096
#define DY 8
#define NBQ (BB * NQ)           // 16384 queries total

#if __has_builtin(__builtin_amdgcn_exp2f)
#define EXP2F(x) __builtin_amdgcn_exp2f(x)
#else
#define EXP2F(x) exp2f(x)
#endif

typedef short bf16x8 __attribute__((ext_vector_type(8)));
typedef float f32x4  __attribute__((ext_vector_type(4)));

__device__ __forceinline__ short f2bf(float v) {
    return (short)(__builtin_bit_cast(unsigned, v) >> 16);   // truncate
}
__device__ __forceinline__ unsigned fbits(float v) {
    return __builtin_bit_cast(unsigned, v);
}
// pack hi16(w0) -> low half, hi16(w1) -> high half (bf16 pair dword)
__device__ __forceinline__ unsigned bfpair(float w0, float w1) {
#if __has_builtin(__builtin_amdgcn_perm)
    return __builtin_amdgcn_perm(fbits(w1), fbits(w0), 0x07060302u);
#else
    return (fbits(w1) & 0xFFFF0000u) | (fbits(w0) >> 16);
#endif
}

// ---------------- fast path (MFMA) ----------------
#define GSPLIT 8                     // global context split
#define CCHUNK (NC / GSPLIT)         // 512 contexts per block
#define NPAIR (CCHUNK / 2)           // 256 context pairs per block
#define KSTEPS (CCHUNK / 32)         // 16 mfma k-steps
#define NT 2                         // query tiles per wave
#define QPB 128                      // queries per block: 4 waves x 2 tiles x 16
#define QB (NBQ / QPB)               // 128 query-blocks
#define JS ((size_t)GSPLIT * NBQ)                     // 131072
#define WS_FLOATS ((size_t)(DY + 1) * GSPLIT * NBQ)   // 1.18M floats = 4.7 MB
#define BFR_OFF_BYTES (8u << 20)     // bfrag region at d_ws + 8 MB (512 KB)
#define NGRP (NC / 8)                // 512 groups per batch

// ---- prep: build Ytilde B-fragments for all ctx: bfG[b][g][n][j] bf16 ----
// One thread per context (64 blocks x 256). Fully rewrites the region.
__global__ __launch_bounds__(256) void setconv_prep(
    const float* __restrict__ yc, unsigned short* __restrict__ bfG)
{
    const int T = blockIdx.x * 256 + threadIdx.x;   // 0..16383
    const int b = T >> 12, c = T & 4095;
    const int g = c >> 3, j = c & 7;
    const float4* yp = ((const float4*)yc) + (size_t)(b * NC + c) * 2;
    const float4 A = yp[0], Bv = yp[1];
    unsigned short* dst = bfG + (size_t)(b * NGRP + g) * 128 + j;
    dst[0 * 8] = (unsigned short)f2bf(A.x);
    dst[1 * 8] = (unsigned short)f2bf(A.y);
    dst[2 * 8] = (unsigned short)f2bf(A.z);
    dst[3 * 8] = (unsigned short)f2bf(A.w);
    dst[4 * 8] = (unsigned short)f2bf(Bv.x);
    dst[5 * 8] = (unsigned short)f2bf(Bv.y);
    dst[6 * 8] = (unsigned short)f2bf(Bv.z);
    dst[7 * 8] = (unsigned short)f2bf(Bv.w);
    // cols 8..15: col 8 = 1.0 (density), 9..15 = 0. u32 view, 32 per group.
    unsigned* y32 = (unsigned*)bfG;
#pragma unroll
    for (int i = 0; i < 4; ++i) {
        const int V = T + 16384 * i;                // 0..65535
        const int bg = V >> 5, r = V & 31;          // r = (n-8)*4 + jpair
        y32[(size_t)bg * 64 + 32 + r] = (r < 4) ? 0x3F803F80u : 0u;
    }
}

// grid = QB*GSPLIT = 1024 blocks of 256 = 4 blocks/CU, 16 waves/CU.
__global__ __launch_bounds__(256, 4) void setconv_accum_mfma(
    const float* __restrict__ xq, const float* __restrict__ xc,
    const unsigned short* __restrict__ bfG, const float* __restrict__ lls,
    float* __restrict__ ws)
{
    __shared__ float4 sxp[NPAIR];            // (cx0,cx1,cy0,cy1) 4 KB
    __shared__ float2 shp[NPAIR];            // (hc0,hc1)         2 KB

    const int bid  = blockIdx.x;              // 0..1023
    const int gs   = bid & (GSPLIT - 1);
    const int qb   = bid >> 3;                // 0..127
    const int b    = qb >> 5;                 // 32 q-blocks per batch
    const int tid  = threadIdx.x;
    const int lane = tid & 63;
    const int wv   = tid >> 6;
    const int m    = lane & 15;               // A row / D col index
    const int quad = lane >> 4;

    const float L    = lls[0];
    const float negk = -0.72134752044448f * EXP2F(L * -2.8853900817779268f);

    // ---- stage ctx pairs only (6 KB): tid == pair index ----
    {
        const float4* xcp = (const float4*)(((const float2*)xc) + (size_t)b * NC + gs * CCHUNK);
        const float4 v = xcp[tid];            // (cx0,cy0,cx1,cy1)
        sxp[tid] = make_float4(v.x, v.z, v.y, v.w);
        shp[tid] = make_float2(negk * fmaf(v.x, v.x, v.y * v.y),
                               negk * fmaf(v.z, v.z, v.w * v.w));
    }

    // ---- per-query coefficients: wave wv owns tiles 2wv, 2wv+1 ----
    float a0[NT], a1[NT], a2[NT];
#pragma unroll
    for (int t = 0; t < NT; ++t) {
        const int q = qb * QPB + (wv * NT + t) * 16 + m;
        const float2 qv = ((const float2*)xq)[q];
        a0[t] = negk * fmaf(qv.x, qv.x, qv.y * qv.y);
        a1[t] = -2.f * negk * qv.x;
        a2[t] = -2.f * negk * qv.y;
    }

    f32x4 acc[NT];
#pragma unroll
    for (int t = 0; t < NT; ++t) acc[t] = (f32x4){0.f, 0.f, 0.f, 0.f};

    // B-fragment base for this (batch, chunk): group gi = gs*64 + s*4 + quad
    const unsigned short* bfb = bfG + (size_t)(b * NGRP + gs * (CCHUNK / 8)) * 128;

    __syncthreads();

    // ---- hot loop: 1 coalesced global b128 (bfrag, L2) + 6 DS broadcasts
    //      + 12 fma + 16 exp + 8 perm + 2 MFMA per k-step ----
#pragma unroll 2
    for (int s = 0; s < KSTEPS; ++s) {
        const int pb = s * 16 + quad * 4;
        const bf16x8 bfrag = *(const bf16x8*)(bfb + (size_t)(s * 4 + quad) * 128 + m * 8);
        const float4 xpA = sxp[pb + 0]; const float2 hpA = shp[pb + 0];
        const float4 xpB = sxp[pb + 1]; const float2 hpB = shp[pb + 1];
        const float4 xpC = sxp[pb + 2]; const float2 hpC = shp[pb + 2];
        const float4 xpD = sxp[pb + 3]; const float2 hpD = shp[pb + 3];
#pragma unroll
        for (int t = 0; t < NT; ++t) {
            uint4 au;
            {
                float u = fmaf(a2[t], xpA.z, fmaf(a1[t], xpA.x, a0[t] + hpA.x));
                float v = fmaf(a2[t], xpA.w, fmaf(a1[t], xpA.y, a0[t] + hpA.y));
                au.x = bfpair(EXP2F(u), EXP2F(v));
            }
            {
                float u = fmaf(a2[t], xpB.z, fmaf(a1[t], xpB.x, a0[t] + hpB.x));
                float v = fmaf(a2[t], xpB.w, fmaf(a1[t], xpB.y, a0[t] + hpB.y));
                au.y = bfpair(EXP2F(u), EXP2F(v));
            }
            {
                float u = fmaf(a2[t], xpC.z, fmaf(a1[t], xpC.x, a0[t] + hpC.x));
                float v = fmaf(a2[t], xpC.w, fmaf(a1[t], xpC.y, a0[t] + hpC.y));
                au.z = bfpair(EXP2F(u), EXP2F(v));
            }
            {
                float u = fmaf(a2[t], xpD.z, fmaf(a1[t], xpD.x, a0[t] + hpD.x));
                float v = fmaf(a2[t], xpD.w, fmaf(a1[t], xpD.y, a0[t] + hpD.y));
                au.w = bfpair(EXP2F(u), EXP2F(v));
            }
            const bf16x8 af = __builtin_bit_cast(bf16x8, au);
            acc[t] = __builtin_amdgcn_mfma_f32_16x16x32_bf16(af, bfrag, acc[t], 0, 0, 0);
        }
    }

    // ---- write ws[j][gs][bq]: lane holds D[row=quad*4+r][col=m] ----
    if (m <= 8) {
        const size_t base = (size_t)m * JS + (size_t)gs * NBQ + (size_t)qb * QPB;
#pragma unroll
        for (int t = 0; t < NT; ++t) {
#pragma unroll
            for (int r = 0; r < 4; ++r)
                ws[base + (wv * NT + t) * 16 + quad * 4 + r] = acc[t][r];
        }
    }
}

// Reduce over GSPLIT=8 + normalize (R4/R8/R9-proven). Block: 64 queries,
// 4 groups of 2 splits. Grid = NBQ/64 = 256 blocks.
__global__ __launch_bounds__(256) void setconv_reduce(
    const float* __restrict__ ws, float* __restrict__ out)
{
    __shared__ float part[4][64][DY + 1];
    const int tid  = threadIdx.x;
    const int qi   = tid & 63;
    const int sg   = tid >> 6;
    const int base = blockIdx.x * 64;
    const int bq   = base + qi;

#pragma unroll
    for (int j = 0; j < DY + 1; ++j) {
        float s = 0.f;
#pragma unroll
        for (int k = 0; k < GSPLIT / 4; ++k) {
            const int split = sg * (GSPLIT / 4) + k;
            s += ws[(size_t)j * JS + (size_t)split * NBQ + bq];  // coalesced
        }
        part[sg][qi][j] = s;
    }
    __syncthreads();

    for (int it = tid; it < 64 * (DY + 1); it += 256) {
        const int q2 = it / (DY + 1);
        const int j  = it - q2 * (DY + 1);
        const float den = part[0][q2][DY] + part[1][q2][DY] +
                          part[2][q2][DY] + part[3][q2][DY];
        float v;
        if (j == DY) {
            v = den;
        } else {
            const float s = part[0][q2][j] + part[1][q2][j] +
                            part[2][q2][j] + part[3][q2][j];
            v = s / (den + 1e-8f);
        }
        out[(size_t)base * (DY + 1) + it] = v;    // coalesced
    }
}

// ---------------- fallback path (round-1, known-good): atomics ----------------
#define FSPLIT 8
#define FCCH (NC / FSPLIT)

__global__ __launch_bounds__(256) void setconv_zero(float4* __restrict__ out) {
    out[blockIdx.x * 256 + threadIdx.x] = make_float4(0.f, 0.f, 0.f, 0.f);
}

__global__ __launch_bounds__(256) void setconv_accum_atomic(
    const float* __restrict__ xq, const float* __restrict__ xc,
    const float* __restrict__ yc, const float* __restrict__ lls,
    float* __restrict__ out)
{
    const int bid   = blockIdx.x;
    const int split = bid & (FSPLIT - 1);
    const int qblk  = (bid / FSPLIT) & (NQ / 256 - 1);
    const int b     = bid / (FSPLIT * (NQ / 256));
    const int q     = qblk * 256 + threadIdx.x;

    const float L    = lls[0];
    const float negk = -0.72134752044448f * EXP2F(L * -2.8853900817779268f);

    const float2 qv = ((const float2*)xq)[b * NQ + q];
    const float qx0 = qv.x, qy0 = qv.y;

    float acc[DY], den = 0.f;
#pragma unroll
    for (int j = 0; j < DY; ++j) acc[j] = 0.f;

    const float2* __restrict__ xcp = ((const float2*)xc) + (size_t)b * NC;
    const float4* __restrict__ ycp = ((const float4*)yc) + (size_t)b * NC * 2;

    const int c0 = split * FCCH;
#pragma unroll 4
    for (int c = c0; c < c0 + FCCH; ++c) {
        const float2 cv = xcp[c];
        const float4 y0 = ycp[2 * c + 0];
        const float4 y1 = ycp[2 * c + 1];
        const float dx = qx0 - cv.x;
        const float dy = qy0 - cv.y;
        const float d2 = fmaf(dy, dy, dx * dx);
        const float w  = EXP2F(d2 * negk);
        den += w;
        acc[0] = fmaf(w, y0.x, acc[0]);
        acc[1] = fmaf(w, y0.y, acc[1]);
        acc[2] = fmaf(w, y0.z, acc[2]);
        acc[3] = fmaf(w, y0.w, acc[3]);
        acc[4] = fmaf(w, y1.x, acc[4]);
        acc[5] = fmaf(w, y1.y, acc[5]);
        acc[6] = fmaf(w, y1.z, acc[6]);
        acc[7] = fmaf(w, y1.w, acc[7]);
    }

    float* o = out + (size_t)(b * NQ + q) * (DY + 1);
#pragma unroll
    for (int j = 0; j < DY; ++j) atomicAdd(o + j, acc[j]);
    atomicAdd(o + DY, den);
}

__global__ __launch_bounds__(256) void setconv_norm(float* __restrict__ out) {
    const int q = blockIdx.x * 256 + threadIdx.x;
    float* o = out + (size_t)q * (DY + 1);
    const float inv = 1.0f / (o[DY] + 1e-8f);
#pragma unroll
    for (int j = 0; j < DY; ++j) o[j] *= inv;
}

extern "C" void kernel_launch(void* const* d_in, const int* in_sizes, int n_in,
                              void* d_out, int out_size, void* d_ws, size_t ws_size,
                              hipStream_t stream) {
    const float* xq  = (const float*)d_in[0];  // (4,4096,2)
    const float* xc  = (const float*)d_in[1];  // (4,4096,2)
    const float* yc  = (const float*)d_in[2];  // (4,4096,8)
    const float* lls = (const float*)d_in[3];  // scalar
    float* out = (float*)d_out;                // (4,4096,9)

    if (ws_size >= BFR_OFF_BYTES + (1u << 20)) {
        float* ws = (float*)d_ws;
        unsigned short* bfG = (unsigned short*)((char*)d_ws + BFR_OFF_BYTES);
        setconv_prep<<<NBQ / 256, 256, 0, stream>>>(yc, bfG);
        setconv_accum_mfma<<<QB * GSPLIT, 256, 0, stream>>>(xq, xc, bfG, lls, ws);
        setconv_reduce<<<NBQ / 64, 256, 0, stream>>>(ws, out);
    } else {
        setconv_zero<<<(NBQ * (DY + 1)) / 1024, 256, 0, stream>>>((float4*)out);
        setconv_accum_atomic<<<BB * (NQ / 256) * FSPLIT, 256, 0, stream>>>(xq, xc, yc, lls, out);
        setconv_norm<<<NBQ / 256, 256, 0, stream>>>(out);
    }
}